// Round 23
// baseline (373.902 us; speedup 1.0000x reference)
//
#include <hip/hip_runtime.h>
#include <hip/hip_bf16.h>
#include <math.h>

// Problem constants
#define MTOT   100352        // B*H*W tokens = 2048 windows * 49
#define MP     784           // M panels (MTOT/128)
#define CC     192
#define SCALEQ 0.17677669529663687f   // 32^-0.5

typedef __attribute__((ext_vector_type(8))) short short8;
typedef __attribute__((ext_vector_type(4))) float f32x4;

__device__ __forceinline__ float b2f(unsigned short u) {
  return __uint_as_float(((unsigned int)u) << 16);
}

// Fast GELU (tanh form, hardware exp). Max |err| vs exact ~3e-3.
__device__ __forceinline__ float fast_gelu(float z) {
  float u = 1.5957691216f * (z + 0.044715f * z * z * z);
  float e = __expf(u);
  return z - z / (1.f + e);
}

// float -> OCP e4m3 fp8 via HW v_cvt_pk_fp8_f32 (gfx950 native format)
__device__ __forceinline__ unsigned char f2fp8(float z) {
  return (unsigned char)(__builtin_amdgcn_cvt_pk_fp8_f32(z, z, 0, false) & 0xff);
}

__device__ __forceinline__ void async_copy16(const void* g, void* l) {
  __builtin_amdgcn_global_load_lds(
      (const __attribute__((address_space(1))) unsigned int*)g,
      (__attribute__((address_space(3))) unsigned int*)l,
      16, 0, 0);
}

// ---------------------------------------------------------------------------
// Weight fp32 -> bf16 conversion (qkv | proj | fc1 concatenated into dst)
// ---------------------------------------------------------------------------
__global__ void cvt4_kernel(const float* __restrict__ s0, int n0,
                            const float* __restrict__ s1, int n1,
                            const float* __restrict__ s2, int n2,
                            __hip_bfloat16* __restrict__ dst)
{
  int total = n0 + n1 + n2;
  for (int i = blockIdx.x * blockDim.x + threadIdx.x; i < total;
       i += gridDim.x * blockDim.x) {
    int j = i; const float* s;
    if (j < n0) s = s0;
    else { j -= n0; if (j < n1) s = s1; else { j -= n1; s = s2; } }
    dst[i] = __float2bfloat16(s[j]);
  }
}

// W2 fp32 -> fp8 e4m3, scaled x16 (keeps ~0.02-scale weights normal-range)
__global__ void cvtw2_kernel(const float* __restrict__ w,
                             unsigned char* __restrict__ dst)
{
  int i = blockIdx.x * 256 + threadIdx.x;
  if (i < 192 * 768) dst[i] = f2fp8(w[i] * 16.f);
}

// ---------------------------------------------------------------------------
// Softmax-bias table: tab[wm][head][q64][k64] = rpb(q,k,head) + mask[wm][q][k]
// ---------------------------------------------------------------------------
__global__ __launch_bounds__(256)
void smtab_kernel(const float* __restrict__ mask, const float* __restrict__ rpb,
                  __hip_bfloat16* __restrict__ tab)
{
  const int wh = blockIdx.x;          // 0..383 = wm*6 + head
  const int wm = wh / 6, head = wh - wm * 6;
  for (int u = threadIdx.x; u < 4096; u += 256) {
    int q = u >> 6, k = u & 63;
    float v = -1e30f;
    if (q < 49 && k < 49) {
      int r1 = q / 7, s1 = q - r1 * 7, r2 = k / 7, s2 = k - r2 * 7;
      v = rpb[((r1 - r2 + 6) * 13 + (s1 - s2 + 6)) * 6 + head]
        + mask[wm * 2401 + q * 49 + k];
    }
    tab[(size_t)wh * 4096 + u] = __float2bfloat16(v);
  }
}

// ---------------------------------------------------------------------------
// LayerNorm (one wave per token). REMAP: fused roll(-3,-3)+window partition
// (LN1, fp32 input). BF16IN: input rows are bf16 (LN2 on bf16 x2).
// ---------------------------------------------------------------------------
template<bool REMAP, bool BF16IN>
__global__ __launch_bounds__(256)
void ln_kernel(const void* __restrict__ xin, const float* __restrict__ gam,
               const float* __restrict__ bet, __hip_bfloat16* __restrict__ out)
{
  const int wave = threadIdx.x >> 6, lane = threadIdx.x & 63;
  const int m = blockIdx.x * 4 + wave;
  size_t srow;
  if (REMAP) {
    int b_ = m / 49, n = m - b_ * 49;
    int b = b_ >> 6, widx = b_ & 63;
    int wh = widx >> 3, ww = widx & 7;
    int r = n / 7, s = n - r * 7;
    int h = wh * 7 + r, w = ww * 7 + s;
    int sh = h + 3; if (sh >= 56) sh -= 56;
    int sw = w + 3; if (sw >= 56) sw -= 56;
    srow = (size_t)b * 3136 + sh * 56 + sw;
  } else {
    srow = m;
  }
  float v0, v1, v2;
  if (BF16IN) {
    const unsigned short* row = (const unsigned short*)xin + srow * 192;
    v0 = b2f(row[lane]); v1 = b2f(row[lane + 64]); v2 = b2f(row[lane + 128]);
  } else {
    const float* row = (const float*)xin + srow * 192;
    v0 = row[lane]; v1 = row[lane + 64]; v2 = row[lane + 128];
  }
  float sum = v0 + v1 + v2;
  float sq  = v0 * v0 + v1 * v1 + v2 * v2;
  #pragma unroll
  for (int o = 1; o < 64; o <<= 1) {
    sum += __shfl_xor(sum, o);
    sq  += __shfl_xor(sq, o);
  }
  float mu = sum * (1.f / 192.f);
  float rs = rsqrtf(sq * (1.f / 192.f) - mu * mu + 1e-5f);
  __hip_bfloat16* orow = out + (size_t)m * 192;
  orow[lane]       = __float2bfloat16((v0 - mu) * rs * gam[lane]       + bet[lane]);
  orow[lane + 64]  = __float2bfloat16((v1 - mu) * rs * gam[lane + 64]  + bet[lane + 64]);
  orow[lane + 128] = __float2bfloat16((v2 - mu) * rs * gam[lane + 128] + bet[lane + 128]);
}

// ---------------------------------------------------------------------------
// BARRIER-FREE bf16 MFMA GEMM:
// A panel (128 x K, 48 KB for K=192) staged to LDS ONCE (linear dest,
// inverse-swizzled source, rule #21); then NTPB N-tiles x K fully unrolled
// with NO __syncthreads: A frags from LDS (2-way alias max = free, m136),
// B frags per-lane from L2-hot weights (wave = 16 rows x 64 B, coalesced).
// Compiler pipelines loads across MFMAs freely (no barrier drain).
// NBLK blocks per panel; XCD-coherent panel mapping (A fetched once/XCD).
// EPI: 0 = store bf16 (qkv)
//      1 = fast GELU, store FP8 e4m3 (fc1 -> h)
//      4 = proj: window-reverse + roll + residual(fp32 x) -> bf16 x2
// ---------------------------------------------------------------------------
template<int EPI, int K, int NTPB, int NBLK>
__global__ __launch_bounds__(256)
void gemm_kernel(const __hip_bfloat16* __restrict__ A,
                 const __hip_bfloat16* __restrict__ Wt,
                 const float* __restrict__ bias,
                 int Ntot,
                 void* __restrict__ outp,
                 const void* __restrict__ res)
{
  __shared__ __hip_bfloat16 As[128 * K] __attribute__((aligned(16)));
  const int tid  = threadIdx.x;
  const int wave = tid >> 6;
  const int bid   = blockIdx.x;
  const int xcd   = bid & 7;
  const int j     = bid >> 3;
  const int panel = xcd * (MP / 8) + j / NBLK;
  const int bn0   = (j % NBLK) * NTPB * 64;
  const int bm    = panel * 128;

  const int lr = tid & 15;
  const int hi = (tid >> 4) & 3;
  const int wm = (wave >> 1) * 64;
  const int wn = (wave & 1) * 32;

  // ---- stage full A panel: 128*K/8 chunks, linear dest, swizzled source ----
  constexpr int CH = K / 8;                  // chunks per row
  constexpr int PASSES = 128 * CH / 256;
  #pragma unroll
  for (int p = 0; p < PASSES; p++) {
    int u = p * 256 + tid;
    int row = u / CH, c = u % CH;
    int csw = (c & ~7) | ((c & 7) ^ (row & 7));
    async_copy16(A + (size_t)(bm + row) * K + csw * 8, &As[u * 8]);
  }
  __syncthreads();                           // the ONLY barrier

  #pragma unroll
  for (int nt = 0; nt < NTPB; nt++) {
    const int bn = bn0 + nt * 64;
    f32x4 acc[4][2];
    #pragma unroll
    for (int i = 0; i < 4; i++)
      #pragma unroll
      for (int j2 = 0; j2 < 2; j2++) acc[i][j2] = (f32x4){0.f, 0.f, 0.f, 0.f};

    #pragma unroll
    for (int kt = 0; kt < K / 64; kt++) {
      #pragma unroll
      for (int kk = 0; kk < 2; kk++) {
        short8 af[4], bfr[2];
        #pragma unroll
        for (int nf = 0; nf < 2; nf++) {
          int n = bn + wn + nf * 16 + lr;
          bfr[nf] = *(const short8*)(Wt + (size_t)n * K + kt * 64 + kk * 32 + hi * 8);
        }
        #pragma unroll
        for (int mf = 0; mf < 4; mf++) {
          int r = wm + mf * 16 + lr;
          int ch = kt * 8 + kk * 4 + hi;
          int chs = (ch & ~7) | ((ch & 7) ^ (r & 7));
          af[mf] = *(const short8*)&As[r * K + chs * 8];
        }
        #pragma unroll
        for (int mf = 0; mf < 4; mf++)
          #pragma unroll
          for (int nf = 0; nf < 2; nf++)
            acc[mf][nf] = __builtin_amdgcn_mfma_f32_16x16x32_bf16(
                af[mf], bfr[nf], acc[mf][nf], 0, 0, 0);
      }
    }

    // Epilogue. C/D layout: col = lane&15, row = (lane>>4)*4 + reg.
    #pragma unroll
    for (int mf = 0; mf < 4; mf++) {
      #pragma unroll
      for (int nf = 0; nf < 2; nf++) {
        #pragma unroll
        for (int r = 0; r < 4; r++) {
          int m = bm + wm + mf * 16 + hi * 4 + r;
          int n = bn + wn + nf * 16 + lr;
          float z = acc[mf][nf][r] + bias[n];
          if (EPI == 0) {
            ((__hip_bfloat16*)outp)[(size_t)m * Ntot + n] = __float2bfloat16(z);
          } else if (EPI == 1) {
            ((unsigned char*)outp)[(size_t)m * Ntot + n] = f2fp8(fast_gelu(z));
          } else {  // EPI == 4: proj + window-reverse + unshift + residual
            int b_ = m / 49, n49 = m - b_ * 49;
            int b = b_ >> 6, widx = b_ & 63;
            int wh = widx >> 3, ww = widx & 7;
            int rr = n49 / 7, ss = n49 - rr * 7;
            int h = wh * 7 + rr, w = ww * 7 + ss;
            int fh = h + 3; if (fh >= 56) fh -= 56;
            int fw = w + 3; if (fw >= 56) fw -= 56;
            size_t rowimg = (size_t)b * 3136 + fh * 56 + fw;
            float v = ((const float*)res)[rowimg * 192 + n] + z;
            ((__hip_bfloat16*)outp)[rowimg * 192 + n] = __float2bfloat16(v);
          }
        }
      }
    }
  }
}

// ---------------------------------------------------------------------------
// FP8 MFMA GEMM for fc2: out = (h_fp8 @ W2_fp8^T)/16 + b2 + x2b  (validated r22)
// ---------------------------------------------------------------------------
__global__ __launch_bounds__(256)
void gemm8_kernel(const unsigned char* __restrict__ A8,
                  const unsigned char* __restrict__ W28,
                  const float* __restrict__ bias,
                  const unsigned short* __restrict__ res,  // x2b bf16
                  float* __restrict__ out)
{
  __shared__ unsigned char smem8[2][12288] __attribute__((aligned(16)));
  const int tid  = threadIdx.x;
  const int wave = tid >> 6;
  const int bid   = blockIdx.x;
  const int xcd   = bid & 7;
  const int j     = bid >> 3;
  const int panel = xcd * (MP / 8) + j / 3;
  const int bn    = (j % 3) * 64;
  const int bm    = panel * 128;

  const int lr = tid & 15;
  const int hi = (tid >> 4) & 3;
  const int wm = (wave >> 1) * 64;
  const int wn = (wave & 1) * 32;

  const unsigned char* aptr[2];
  const unsigned char* bptr;
  int adst[2], bdst;
  #pragma unroll
  for (int p = 0; p < 2; p++) {
    int u = p * 256 + tid;              // chunk 0..511 (A: 128 rows x 4)
    int row = u >> 2, c4 = u & 3;
    int sw = (row & 3) ^ ((row >> 2) & 3);
    aptr[p] = A8 + (size_t)(bm + row) * 768 + ((c4 ^ sw) << 4);
    adst[p] = u << 4;
  }
  {
    int row = tid >> 2, c4 = tid & 3;   // B: 64 rows x 4 chunks
    int sw = (row & 3) ^ ((row >> 2) & 3);
    bptr = W28 + (size_t)(bn + row) * 768 + ((c4 ^ sw) << 4);
    bdst = 8192 + (tid << 4);
  }

  f32x4 acc[4][2];
  #pragma unroll
  for (int i = 0; i < 4; i++)
    #pragma unroll
    for (int j2 = 0; j2 < 2; j2++) acc[i][j2] = (f32x4){0.f, 0.f, 0.f, 0.f};

  #define STAGE8(buf, k0)                                                     \
    do {                                                                      \
      async_copy16(aptr[0] + (k0), &smem8[buf][adst[0]]);                     \
      async_copy16(aptr[1] + (k0), &smem8[buf][adst[1]]);                     \
      async_copy16(bptr + (k0), &smem8[buf][bdst]);                           \
    } while (0)

  STAGE8(0, 0);
  __syncthreads();

  #pragma unroll
  for (int kt = 0; kt < 12; kt++) {     // K=768, 64/step
    const int cur = kt & 1;
    if (kt + 1 < 12) STAGE8(cur ^ 1, (kt + 1) * 64);
    const unsigned char* sb = smem8[cur];
    #pragma unroll
    for (int kk = 0; kk < 2; kk++) {
      long af[4], bf8[2];
      #pragma unroll
      for (int mf = 0; mf < 4; mf++) {
        int r = wm + mf * 16 + lr;
        int sw = (r & 3) ^ ((r >> 2) & 3);
        int ch = kk * 2 + (hi >> 1);
        af[mf] = *(const long*)&sb[r * 64 + ((ch ^ sw) << 4) + ((hi & 1) << 3)];
      }
      #pragma unroll
      for (int nf = 0; nf < 2; nf++) {
        int r = wn + nf * 16 + lr;
        int sw = (r & 3) ^ ((r >> 2) & 3);
        int ch = kk * 2 + (hi >> 1);
        bf8[nf] = *(const long*)&sb[8192 + r * 64 + ((ch ^ sw) << 4) + ((hi & 1) << 3)];
      }
      #pragma unroll
      for (int mf = 0; mf < 4; mf++)
        #pragma unroll
        for (int nf = 0; nf < 2; nf++)
          acc[mf][nf] = __builtin_amdgcn_mfma_f32_16x16x32_fp8_fp8(
              af[mf], bf8[nf], acc[mf][nf], 0, 0, 0);
    }
    __syncthreads();
  }
  #undef STAGE8

  // Epilogue: /16 (W2 scale) + bias + bf16 residual -> fp32 out
  #pragma unroll
  for (int mf = 0; mf < 4; mf++) {
    #pragma unroll
    for (int nf = 0; nf < 2; nf++) {
      #pragma unroll
      for (int r = 0; r < 4; r++) {
        int m = bm + wm + mf * 16 + hi * 4 + r;
        int n = bn + wn + nf * 16 + lr;
        out[(size_t)m * 192 + n] =
            acc[mf][nf][r] * 0.0625f + bias[n] + b2f(res[(size_t)m * 192 + n]);
      }
    }
  }
}

// ---------------------------------------------------------------------------
// MFMA windowed attention: one wave per (window, head). Padded 49->64.
// ---------------------------------------------------------------------------
__global__ __launch_bounds__(64)
void attn_kernel(const __hip_bfloat16* __restrict__ qkv,
                 const __hip_bfloat16* __restrict__ smtab, // [64][6][64][64]
                 __hip_bfloat16* __restrict__ o)           // [MTOT][192]
{
  __shared__ char lds[12288] __attribute__((aligned(16)));  // P:0..8191 | vT:8192..12287
  const int b_   = blockIdx.x;
  const int head = blockIdx.y;
  const int l = threadIdx.x, c = l & 15, h = l >> 4;
  const size_t base = (size_t)b_ * 49 * 576;
  const int headoff = head * 32;

  // ---- stage V^T into LDS (keys >= 49 zeroed), swizzle byte^=((d&7)<<4) ----
  #pragma unroll
  for (int it = 0; it < 4; it++) {
    int u = l + it * 64;
    int row = u >> 2, c8 = u & 3;          // row = key 0..63, c8 = d-chunk
    short8 vv;
    if (row < 49) {
      vv = *(const short8*)(qkv + base + (size_t)row * 576 + 384 + headoff + c8 * 8);
    } else {
      #pragma unroll
      for (int e = 0; e < 8; e++) vv[e] = 0;
    }
    #pragma unroll
    for (int e = 0; e < 8; e++) {
      int d = c8 * 8 + e;
      *(short*)(lds + 8192 + ((d * 128 + row * 2) ^ ((d & 7) << 4))) = vv[e];
    }
  }

  // ---- Q,K fragments direct from global ----
  short8 aq[4], bk[4];
  #pragma unroll
  for (int t = 0; t < 4; t++) {
    int rowc = c + 16 * t; if (rowc > 48) rowc = 48;   // clamp padded rows
    const __hip_bfloat16* rp = qkv + base + (size_t)rowc * 576 + headoff + h * 8;
    aq[t] = *(const short8*)rp;          // Q
    bk[t] = *(const short8*)(rp + 192);  // K
  }

  // ---- S = Q*K^T : 16 MFMA ----
  f32x4 sacc[4][4];
  #pragma unroll
  for (int mi = 0; mi < 4; mi++)
    #pragma unroll
    for (int ni = 0; ni < 4; ni++)
      sacc[mi][ni] = (f32x4){0.f, 0.f, 0.f, 0.f};
  #pragma unroll
  for (int mi = 0; mi < 4; mi++)
    #pragma unroll
    for (int ni = 0; ni < 4; ni++)
      sacc[mi][ni] = __builtin_amdgcn_mfma_f32_16x16x32_bf16(
          aq[mi], bk[ni], sacc[mi][ni], 0, 0, 0);

  // ---- bias table + row softmax + P -> LDS ----
  const unsigned short* tb =
      (const unsigned short*)smtab + (((size_t)(b_ & 63) * 6 + head) << 12);
  float inv[4][4];
  #pragma unroll
  for (int mi = 0; mi < 4; mi++) {
    #pragma unroll
    for (int r = 0; r < 4; r++) {
      const int row = mi * 16 + h * 4 + r;   // query row (C-layout)
      float s[4];
      #pragma unroll
      for (int ni = 0; ni < 4; ni++)
        s[ni] = fmaf(sacc[mi][ni][r], SCALEQ, b2f(tb[row * 64 + ni * 16 + c]));
      float vmax = fmaxf(fmaxf(s[0], s[1]), fmaxf(s[2], s[3]));
      #pragma unroll
      for (int off = 1; off < 16; off <<= 1)
        vmax = fmaxf(vmax, __shfl_xor(vmax, off));
      float p[4], vsum = 0.f;
      #pragma unroll
      for (int ni = 0; ni < 4; ni++) { p[ni] = __expf(s[ni] - vmax); vsum += p[ni]; }
      #pragma unroll
      for (int off = 1; off < 16; off <<= 1)
        vsum += __shfl_xor(vsum, off);
      inv[mi][r] = 1.f / vsum;
      #pragma unroll
      for (int ni = 0; ni < 4; ni++) {
        int col = ni * 16 + c;
        *(__hip_bfloat16*)(lds + ((row * 128 + col * 2) ^ ((row & 7) << 4))) =
            __float2bfloat16(p[ni]);
      }
    }
  }
  __syncthreads();

  // ---- O = P*V ----
  f32x4 oacc[4][2];
  #pragma unroll
  for (int mt = 0; mt < 4; mt++)
    #pragma unroll
    for (int nt = 0; nt < 2; nt++)
      oacc[mt][nt] = (f32x4){0.f, 0.f, 0.f, 0.f};
  #pragma unroll
  for (int ks = 0; ks < 2; ks++) {
    short8 vb[2];
    #pragma unroll
    for (int nt = 0; nt < 2; nt++) {
      int d = c + 16 * nt;
      vb[nt] = *(const short8*)(lds + 8192 +
                ((d * 128 + h * 16 + ks * 64) ^ ((d & 7) << 4)));
    }
    #pragma unroll
    for (int mt = 0; mt < 4; mt++) {
      int qr = c + 16 * mt;
      short8 pa = *(const short8*)(lds +
                   ((qr * 128 + h * 16 + ks * 64) ^ ((qr & 7) << 4)));
      #pragma unroll
      for (int nt = 0; nt < 2; nt++)
        oacc[mt][nt] = __builtin_amdgcn_mfma_f32_16x16x32_bf16(
            pa, vb[nt], oacc[mt][nt], 0, 0, 0);
    }
  }

  // ---- store (q < 49 only), normalize by 1/rowsum ----
  #pragma unroll
  for (int mt = 0; mt < 4; mt++) {
    #pragma unroll
    for (int r = 0; r < 4; r++) {
      int q = mt * 16 + h * 4 + r;
      if (q < 49) {
        __hip_bfloat16* orow = o + ((size_t)b_ * 49 + q) * 192 + headoff;
        #pragma unroll
        for (int nt = 0; nt < 2; nt++)
          orow[nt * 16 + c] = __float2bfloat16(oacc[mt][nt][r] * inv[mt][r]);
      }
    }
  }
}

// ---------------------------------------------------------------------------
extern "C" void kernel_launch(void* const* d_in, const int* in_sizes, int n_in,
                              void* d_out, int out_size, void* d_ws, size_t ws_size,
                              hipStream_t stream)
{
  const float* x      = (const float*)d_in[0];
  const float* mask   = (const float*)d_in[1];
  const float* n1g    = (const float*)d_in[2];
  const float* n1b    = (const float*)d_in[3];
  const float* qkv_w  = (const float*)d_in[4];
  const float* qkv_b  = (const float*)d_in[5];
  const float* proj_w = (const float*)d_in[6];
  const float* proj_b = (const float*)d_in[7];
  const float* rpb    = (const float*)d_in[8];
  const float* n2g    = (const float*)d_in[9];
  const float* n2b    = (const float*)d_in[10];
  const float* fc1_w  = (const float*)d_in[11];
  const float* fc1_b  = (const float*)d_in[12];
  const float* fc2_w  = (const float*)d_in[13];
  const float* fc2_b  = (const float*)d_in[14];
  float* out = (float*)d_out;

  // Workspace layout:
  //   A: 154.1 MB (qkv out bf16; later h fp8 [MTOT][768] = 77 MB)
  //   B:  38.5 MB (xw, attn-out, LN2 out)
  //   W:  0.7 MB bf16 weights (qkv|proj|fc1)   T: 3.1 MB softmax table
  //   X:  38.5 MB bf16 x2 residual   W8: 0.15 MB fp8 W2
  const size_t offA = 0;
  const size_t offB = offA + (size_t)100352 * 768 * 2;
  const size_t offW = offB + (size_t)100352 * 192 * 2;
  const size_t offT = offW + (size_t)(576*192 + 192*192 + 768*192) * 2;
  const size_t offX = offT + (size_t)384 * 4096 * 2;
  const size_t offW8 = offX + (size_t)100352 * 192 * 2;
  const size_t need = offW8 + (size_t)192 * 768;
  if (ws_size < need) return;  // avoid OOB writes

  char* ws = (char*)d_ws;
  __hip_bfloat16* bufA = (__hip_bfloat16*)(ws + offA);
  unsigned char*  h8   = (unsigned char*)(ws + offA);   // fc1 out (reuses A)
  __hip_bfloat16* bufB = (__hip_bfloat16*)(ws + offB);
  __hip_bfloat16* wq   = (__hip_bfloat16*)(ws + offW);
  __hip_bfloat16* wp   = wq + 576 * 192;
  __hip_bfloat16* w1   = wp + 192 * 192;
  __hip_bfloat16* tab  = (__hip_bfloat16*)(ws + offT);
  __hip_bfloat16* x2b  = (__hip_bfloat16*)(ws + offX);
  unsigned char*  w28  = (unsigned char*)(ws + offW8);

  // 1. weights -> bf16 (qkv|proj|fc1) and fc2 -> fp8 (x16)
  cvt4_kernel<<<1152, 256, 0, stream>>>(qkv_w, 576 * 192, proj_w, 192 * 192,
                                        fc1_w, 768 * 192, wq);
  cvtw2_kernel<<<576, 256, 0, stream>>>(fc2_w, w28);
  // 1b. softmax bias table
  smtab_kernel<<<384, 256, 0, stream>>>(mask, rpb, tab);
  // 2. LN1 + shift + window partition -> bf16 [MTOT][192]
  ln_kernel<true, false><<<MTOT / 4, 256, 0, stream>>>(x, n1g, n1b, bufB);
  // 3. qkv GEMM (barrier-free, 3 blk/panel x 3 tiles) -> bf16 [MTOT][576]
  gemm_kernel<0, 192, 3, 3><<<MP * 3, 256, 0, stream>>>(
      bufB, wq, qkv_b, 576, bufA, nullptr);
  // 4. windowed attention (MFMA) -> bf16 [MTOT][192]
  attn_kernel<<<dim3(2048, 6), 64, 0, stream>>>(bufA, tab, bufB);
  // 5. proj (barrier-free, 3 blk/panel x 1 tile) -> bf16 x2
  gemm_kernel<4, 192, 1, 3><<<MP * 3, 256, 0, stream>>>(
      bufB, wp, proj_b, 192, x2b, x);
  // 6. LN2 (bf16 input) -> bf16
  ln_kernel<false, true><<<MTOT / 4, 256, 0, stream>>>(x2b, n2g, n2b, bufB);
  // 7. fc1 + fast GELU (barrier-free, 3 blk/panel x 4 tiles) -> FP8 h
  gemm_kernel<1, 192, 4, 3><<<MP * 3, 256, 0, stream>>>(
      bufB, w1, fc1_b, 768, h8, nullptr);
  // 8. fc2 (fp8 MFMA) + residual(bf16 x2) -> fp32 out (3 N-tiles)
  gemm8_kernel<<<MP * 3, 256, 0, stream>>>(
      h8, w28, fc2_b, (const unsigned short*)x2b, out);
}

// Round 24
// 329.946 us; speedup vs baseline: 1.1332x; 1.1332x over previous
//
#include <hip/hip_runtime.h>
#include <hip/hip_bf16.h>
#include <math.h>

// Problem constants
#define MTOT   100352        // B*H*W tokens = 2048 windows * 49
#define MP     784           // M panels (MTOT/128)
#define CC     192
#define SCALEQ 0.17677669529663687f   // 32^-0.5

typedef __attribute__((ext_vector_type(8))) short short8;
typedef __attribute__((ext_vector_type(4))) float f32x4;

__device__ __forceinline__ float b2f(unsigned short u) {
  return __uint_as_float(((unsigned int)u) << 16);
}

// Sigmoid-GELU: z*sigmoid(1.702z) = z - z/(1+e^{1.702z}).  ~5 VALU ops.
// Max |err| vs exact GELU ~0.02 (propagates <=5e-3 to block output).
__device__ __forceinline__ float fast_gelu(float z) {
  float e = __expf(1.702f * z);
  return z - z / (1.f + e);
}

// float -> OCP e4m3 fp8 via HW v_cvt_pk_fp8_f32 (gfx950 native format)
__device__ __forceinline__ unsigned char f2fp8(float z) {
  return (unsigned char)(__builtin_amdgcn_cvt_pk_fp8_f32(z, z, 0, false) & 0xff);
}

__device__ __forceinline__ void async_copy16(const void* g, void* l) {
  __builtin_amdgcn_global_load_lds(
      (const __attribute__((address_space(1))) unsigned int*)g,
      (__attribute__((address_space(3))) unsigned int*)l,
      16, 0, 0);
}

// ---------------------------------------------------------------------------
// Weight fp32 -> bf16 conversion (qkv | proj | fc1 concatenated into dst)
// ---------------------------------------------------------------------------
__global__ void cvt4_kernel(const float* __restrict__ s0, int n0,
                            const float* __restrict__ s1, int n1,
                            const float* __restrict__ s2, int n2,
                            __hip_bfloat16* __restrict__ dst)
{
  int total = n0 + n1 + n2;
  for (int i = blockIdx.x * blockDim.x + threadIdx.x; i < total;
       i += gridDim.x * blockDim.x) {
    int j = i; const float* s;
    if (j < n0) s = s0;
    else { j -= n0; if (j < n1) s = s1; else { j -= n1; s = s2; } }
    dst[i] = __float2bfloat16(s[j]);
  }
}

// W2 fp32 -> fp8 e4m3, scaled x16 (keeps ~0.02-scale weights normal-range)
__global__ void cvtw2_kernel(const float* __restrict__ w,
                             unsigned char* __restrict__ dst)
{
  int i = blockIdx.x * 256 + threadIdx.x;
  if (i < 192 * 768) dst[i] = f2fp8(w[i] * 16.f);
}

// ---------------------------------------------------------------------------
// Softmax-bias table: tab[wm][head][q64][k64] = rpb(q,k,head) + mask[wm][q][k]
// ---------------------------------------------------------------------------
__global__ __launch_bounds__(256)
void smtab_kernel(const float* __restrict__ mask, const float* __restrict__ rpb,
                  __hip_bfloat16* __restrict__ tab)
{
  const int wh = blockIdx.x;          // 0..383 = wm*6 + head
  const int wm = wh / 6, head = wh - wm * 6;
  for (int u = threadIdx.x; u < 4096; u += 256) {
    int q = u >> 6, k = u & 63;
    float v = -1e30f;
    if (q < 49 && k < 49) {
      int r1 = q / 7, s1 = q - r1 * 7, r2 = k / 7, s2 = k - r2 * 7;
      v = rpb[((r1 - r2 + 6) * 13 + (s1 - s2 + 6)) * 6 + head]
        + mask[wm * 2401 + q * 49 + k];
    }
    tab[(size_t)wh * 4096 + u] = __float2bfloat16(v);
  }
}

// ---------------------------------------------------------------------------
// LayerNorm (one wave per token). REMAP: fused roll(-3,-3)+window partition
// (LN1, fp32 input). BF16IN: input rows are bf16 (LN2 on bf16 x2).
// ---------------------------------------------------------------------------
template<bool REMAP, bool BF16IN>
__global__ __launch_bounds__(256)
void ln_kernel(const void* __restrict__ xin, const float* __restrict__ gam,
               const float* __restrict__ bet, __hip_bfloat16* __restrict__ out)
{
  const int wave = threadIdx.x >> 6, lane = threadIdx.x & 63;
  const int m = blockIdx.x * 4 + wave;
  size_t srow;
  if (REMAP) {
    int b_ = m / 49, n = m - b_ * 49;
    int b = b_ >> 6, widx = b_ & 63;
    int wh = widx >> 3, ww = widx & 7;
    int r = n / 7, s = n - r * 7;
    int h = wh * 7 + r, w = ww * 7 + s;
    int sh = h + 3; if (sh >= 56) sh -= 56;
    int sw = w + 3; if (sw >= 56) sw -= 56;
    srow = (size_t)b * 3136 + sh * 56 + sw;
  } else {
    srow = m;
  }
  float v0, v1, v2;
  if (BF16IN) {
    const unsigned short* row = (const unsigned short*)xin + srow * 192;
    v0 = b2f(row[lane]); v1 = b2f(row[lane + 64]); v2 = b2f(row[lane + 128]);
  } else {
    const float* row = (const float*)xin + srow * 192;
    v0 = row[lane]; v1 = row[lane + 64]; v2 = row[lane + 128];
  }
  float sum = v0 + v1 + v2;
  float sq  = v0 * v0 + v1 * v1 + v2 * v2;
  #pragma unroll
  for (int o = 1; o < 64; o <<= 1) {
    sum += __shfl_xor(sum, o);
    sq  += __shfl_xor(sq, o);
  }
  float mu = sum * (1.f / 192.f);
  float rs = rsqrtf(sq * (1.f / 192.f) - mu * mu + 1e-5f);
  __hip_bfloat16* orow = out + (size_t)m * 192;
  orow[lane]       = __float2bfloat16((v0 - mu) * rs * gam[lane]       + bet[lane]);
  orow[lane + 64]  = __float2bfloat16((v1 - mu) * rs * gam[lane + 64]  + bet[lane + 64]);
  orow[lane + 128] = __float2bfloat16((v2 - mu) * rs * gam[lane + 128] + bet[lane + 128]);
}

// ---------------------------------------------------------------------------
// bf16 MFMA GEMM (r22 champion: 256-thr, dbuf, swizzled, hoisted, XCD map)
// EPI: 0 = store bf16 (qkv)
//      1 = sigmoid GELU, store FP8 e4m3 (fc1 -> h)
//      4 = proj: window-reverse + roll + residual(fp32 x) -> bf16 x2
// ---------------------------------------------------------------------------
template<int EPI, int K, int NTILES>
__global__ __launch_bounds__(256)
void gemm_kernel(const __hip_bfloat16* __restrict__ A,
                 const __hip_bfloat16* __restrict__ Wt,
                 const float* __restrict__ bias,
                 int Ntot,
                 void* __restrict__ outp,
                 const void* __restrict__ res)
{
  __shared__ __hip_bfloat16 smem[2][12288] __attribute__((aligned(16)));
  const int tid  = threadIdx.x;
  const int wave = tid >> 6;
  const int bid   = blockIdx.x;
  const int xcd   = bid & 7;
  const int j     = bid >> 3;
  const int panel = xcd * (MP / 8) + j / NTILES;
  const int bn    = (j % NTILES) * 64;
  const int bm    = panel * 128;

  const int lr = tid & 15;
  const int hi = (tid >> 4) & 3;
  const int wm = (wave >> 1) * 64;
  const int wn = (wave & 1) * 32;

  const __hip_bfloat16* aptr[4];
  const __hip_bfloat16* bptr[2];
  int adst[4], bdst[2];
  #pragma unroll
  for (int p = 0; p < 4; p++) {
    int u = p * 256 + tid;
    int row = u >> 3;
    int c8 = (u & 7) ^ (row & 7);              // inverse swizzle on source
    aptr[p] = A + (size_t)(bm + row) * K + c8 * 8;
    adst[p] = (p * 256 + (wave << 6)) * 8;
  }
  #pragma unroll
  for (int p = 0; p < 2; p++) {
    int u = p * 256 + tid;
    int row = u >> 3;
    int c8 = (u & 7) ^ (row & 7);
    bptr[p] = Wt + (size_t)(bn + row) * K + c8 * 8;
    bdst[p] = 8192 + (p * 256 + (wave << 6)) * 8;
  }

  f32x4 acc[4][2];
  #pragma unroll
  for (int i = 0; i < 4; i++)
    #pragma unroll
    for (int j2 = 0; j2 < 2; j2++) acc[i][j2] = (f32x4){0.f, 0.f, 0.f, 0.f};

  const int KT = K / 64;

  #define STAGE(buf, k0)                                                      \
    do {                                                                      \
      _Pragma("unroll")                                                       \
      for (int p = 0; p < 4; p++)                                             \
        async_copy16(aptr[p] + (k0), &smem[buf][adst[p]]);                    \
      _Pragma("unroll")                                                       \
      for (int p = 0; p < 2; p++)                                             \
        async_copy16(bptr[p] + (k0), &smem[buf][bdst[p]]);                    \
    } while (0)

  STAGE(0, 0);
  __syncthreads();

  #pragma unroll
  for (int kt = 0; kt < KT; kt++) {
    const int cur = kt & 1;
    if (kt + 1 < KT) STAGE(cur ^ 1, (kt + 1) * 64);
    const __hip_bfloat16* sb = smem[cur];
    #pragma unroll
    for (int kk = 0; kk < 2; kk++) {
      short8 af[4], bfr[2];
      #pragma unroll
      for (int mf = 0; mf < 4; mf++) {
        int r = wm + mf * 16 + lr;
        af[mf] = *(const short8*)&sb[r * 64 + ((kk * 32 + hi * 8) ^ ((r & 7) * 8))];
      }
      #pragma unroll
      for (int nf = 0; nf < 2; nf++) {
        int r = wn + nf * 16 + lr;
        bfr[nf] = *(const short8*)&sb[8192 + r * 64 + ((kk * 32 + hi * 8) ^ ((r & 7) * 8))];
      }
      #pragma unroll
      for (int mf = 0; mf < 4; mf++)
        #pragma unroll
        for (int nf = 0; nf < 2; nf++)
          acc[mf][nf] = __builtin_amdgcn_mfma_f32_16x16x32_bf16(
              af[mf], bfr[nf], acc[mf][nf], 0, 0, 0);
    }
    __syncthreads();
  }
  #undef STAGE

  // Epilogue. C/D layout: col = lane&15, row = (lane>>4)*4 + reg.
  #pragma unroll
  for (int mf = 0; mf < 4; mf++) {
    #pragma unroll
    for (int nf = 0; nf < 2; nf++) {
      #pragma unroll
      for (int r = 0; r < 4; r++) {
        int m = bm + wm + mf * 16 + hi * 4 + r;
        int n = bn + wn + nf * 16 + lr;
        float z = acc[mf][nf][r] + bias[n];
        if (EPI == 0) {
          ((__hip_bfloat16*)outp)[(size_t)m * Ntot + n] = __float2bfloat16(z);
        } else if (EPI == 1) {
          ((unsigned char*)outp)[(size_t)m * Ntot + n] = f2fp8(fast_gelu(z));
        } else {  // EPI == 4: proj + window-reverse + unshift + residual
          int b_ = m / 49, n49 = m - b_ * 49;
          int b = b_ >> 6, widx = b_ & 63;
          int wh = widx >> 3, ww = widx & 7;
          int rr = n49 / 7, ss = n49 - rr * 7;
          int h = wh * 7 + rr, w = ww * 7 + ss;
          int fh = h + 3; if (fh >= 56) fh -= 56;
          int fw = w + 3; if (fw >= 56) fw -= 56;
          size_t rowimg = (size_t)b * 3136 + fh * 56 + fw;
          float v = ((const float*)res)[rowimg * 192 + n] + z;
          ((__hip_bfloat16*)outp)[rowimg * 192 + n] = __float2bfloat16(v);
        }
      }
    }
  }
}

// ---------------------------------------------------------------------------
// FP8 MFMA GEMM for fc2: out = (h_fp8 @ W2_fp8^T)/16 + b2 + x2b  (validated r22)
// ---------------------------------------------------------------------------
__global__ __launch_bounds__(256)
void gemm8_kernel(const unsigned char* __restrict__ A8,
                  const unsigned char* __restrict__ W28,
                  const float* __restrict__ bias,
                  const unsigned short* __restrict__ res,  // x2b bf16
                  float* __restrict__ out)
{
  __shared__ unsigned char smem8[2][12288] __attribute__((aligned(16)));
  const int tid  = threadIdx.x;
  const int wave = tid >> 6;
  const int bid   = blockIdx.x;
  const int xcd   = bid & 7;
  const int j     = bid >> 3;
  const int panel = xcd * (MP / 8) + j / 3;
  const int bn    = (j % 3) * 64;
  const int bm    = panel * 128;

  const int lr = tid & 15;
  const int hi = (tid >> 4) & 3;
  const int wm = (wave >> 1) * 64;
  const int wn = (wave & 1) * 32;

  const unsigned char* aptr[2];
  const unsigned char* bptr;
  int adst[2], bdst;
  #pragma unroll
  for (int p = 0; p < 2; p++) {
    int u = p * 256 + tid;              // chunk 0..511 (A: 128 rows x 4)
    int row = u >> 2, c4 = u & 3;
    int sw = (row & 3) ^ ((row >> 2) & 3);
    aptr[p] = A8 + (size_t)(bm + row) * 768 + ((c4 ^ sw) << 4);
    adst[p] = u << 4;
  }
  {
    int row = tid >> 2, c4 = tid & 3;   // B: 64 rows x 4 chunks
    int sw = (row & 3) ^ ((row >> 2) & 3);
    bptr = W28 + (size_t)(bn + row) * 768 + ((c4 ^ sw) << 4);
    bdst = 8192 + (tid << 4);
  }

  f32x4 acc[4][2];
  #pragma unroll
  for (int i = 0; i < 4; i++)
    #pragma unroll
    for (int j2 = 0; j2 < 2; j2++) acc[i][j2] = (f32x4){0.f, 0.f, 0.f, 0.f};

  #define STAGE8(buf, k0)                                                     \
    do {                                                                      \
      async_copy16(aptr[0] + (k0), &smem8[buf][adst[0]]);                     \
      async_copy16(aptr[1] + (k0), &smem8[buf][adst[1]]);                     \
      async_copy16(bptr + (k0), &smem8[buf][bdst]);                           \
    } while (0)

  STAGE8(0, 0);
  __syncthreads();

  #pragma unroll
  for (int kt = 0; kt < 12; kt++) {     // K=768, 64/step
    const int cur = kt & 1;
    if (kt + 1 < 12) STAGE8(cur ^ 1, (kt + 1) * 64);
    const unsigned char* sb = smem8[cur];
    #pragma unroll
    for (int kk = 0; kk < 2; kk++) {
      long af[4], bf8[2];
      #pragma unroll
      for (int mf = 0; mf < 4; mf++) {
        int r = wm + mf * 16 + lr;
        int sw = (r & 3) ^ ((r >> 2) & 3);
        int ch = kk * 2 + (hi >> 1);
        af[mf] = *(const long*)&sb[r * 64 + ((ch ^ sw) << 4) + ((hi & 1) << 3)];
      }
      #pragma unroll
      for (int nf = 0; nf < 2; nf++) {
        int r = wn + nf * 16 + lr;
        int sw = (r & 3) ^ ((r >> 2) & 3);
        int ch = kk * 2 + (hi >> 1);
        bf8[nf] = *(const long*)&sb[8192 + r * 64 + ((ch ^ sw) << 4) + ((hi & 1) << 3)];
      }
      #pragma unroll
      for (int mf = 0; mf < 4; mf++)
        #pragma unroll
        for (int nf = 0; nf < 2; nf++)
          acc[mf][nf] = __builtin_amdgcn_mfma_f32_16x16x32_fp8_fp8(
              af[mf], bf8[nf], acc[mf][nf], 0, 0, 0);
    }
    __syncthreads();
  }
  #undef STAGE8

  // Epilogue: /16 (W2 scale) + bias + bf16 residual -> fp32 out
  #pragma unroll
  for (int mf = 0; mf < 4; mf++) {
    #pragma unroll
    for (int nf = 0; nf < 2; nf++) {
      #pragma unroll
      for (int r = 0; r < 4; r++) {
        int m = bm + wm + mf * 16 + hi * 4 + r;
        int n = bn + wn + nf * 16 + lr;
        out[(size_t)m * 192 + n] =
            acc[mf][nf][r] * 0.0625f + bias[n] + b2f(res[(size_t)m * 192 + n]);
      }
    }
  }
}

// ---------------------------------------------------------------------------
// MFMA windowed attention: one wave per (window, head). Padded 49->64.
// ---------------------------------------------------------------------------
__global__ __launch_bounds__(64)
void attn_kernel(const __hip_bfloat16* __restrict__ qkv,
                 const __hip_bfloat16* __restrict__ smtab, // [64][6][64][64]
                 __hip_bfloat16* __restrict__ o)           // [MTOT][192]
{
  __shared__ char lds[12288] __attribute__((aligned(16)));  // P:0..8191 | vT:8192..12287
  const int b_   = blockIdx.x;
  const int head = blockIdx.y;
  const int l = threadIdx.x, c = l & 15, h = l >> 4;
  const size_t base = (size_t)b_ * 49 * 576;
  const int headoff = head * 32;

  // ---- stage V^T into LDS (keys >= 49 zeroed), swizzle byte^=((d&7)<<4) ----
  #pragma unroll
  for (int it = 0; it < 4; it++) {
    int u = l + it * 64;
    int row = u >> 2, c8 = u & 3;          // row = key 0..63, c8 = d-chunk
    short8 vv;
    if (row < 49) {
      vv = *(const short8*)(qkv + base + (size_t)row * 576 + 384 + headoff + c8 * 8);
    } else {
      #pragma unroll
      for (int e = 0; e < 8; e++) vv[e] = 0;
    }
    #pragma unroll
    for (int e = 0; e < 8; e++) {
      int d = c8 * 8 + e;
      *(short*)(lds + 8192 + ((d * 128 + row * 2) ^ ((d & 7) << 4))) = vv[e];
    }
  }

  // ---- Q,K fragments direct from global ----
  short8 aq[4], bk[4];
  #pragma unroll
  for (int t = 0; t < 4; t++) {
    int rowc = c + 16 * t; if (rowc > 48) rowc = 48;   // clamp padded rows
    const __hip_bfloat16* rp = qkv + base + (size_t)rowc * 576 + headoff + h * 8;
    aq[t] = *(const short8*)rp;          // Q
    bk[t] = *(const short8*)(rp + 192);  // K
  }

  // ---- S = Q*K^T : 16 MFMA ----
  f32x4 sacc[4][4];
  #pragma unroll
  for (int mi = 0; mi < 4; mi++)
    #pragma unroll
    for (int ni = 0; ni < 4; ni++)
      sacc[mi][ni] = (f32x4){0.f, 0.f, 0.f, 0.f};
  #pragma unroll
  for (int mi = 0; mi < 4; mi++)
    #pragma unroll
    for (int ni = 0; ni < 4; ni++)
      sacc[mi][ni] = __builtin_amdgcn_mfma_f32_16x16x32_bf16(
          aq[mi], bk[ni], sacc[mi][ni], 0, 0, 0);

  // ---- bias table + row softmax + P -> LDS ----
  const unsigned short* tb =
      (const unsigned short*)smtab + (((size_t)(b_ & 63) * 6 + head) << 12);
  float inv[4][4];
  #pragma unroll
  for (int mi = 0; mi < 4; mi++) {
    #pragma unroll
    for (int r = 0; r < 4; r++) {
      const int row = mi * 16 + h * 4 + r;   // query row (C-layout)
      float s[4];
      #pragma unroll
      for (int ni = 0; ni < 4; ni++)
        s[ni] = fmaf(sacc[mi][ni][r], SCALEQ, b2f(tb[row * 64 + ni * 16 + c]));
      float vmax = fmaxf(fmaxf(s[0], s[1]), fmaxf(s[2], s[3]));
      #pragma unroll
      for (int off = 1; off < 16; off <<= 1)
        vmax = fmaxf(vmax, __shfl_xor(vmax, off));
      float p[4], vsum = 0.f;
      #pragma unroll
      for (int ni = 0; ni < 4; ni++) { p[ni] = __expf(s[ni] - vmax); vsum += p[ni]; }
      #pragma unroll
      for (int off = 1; off < 16; off <<= 1)
        vsum += __shfl_xor(vsum, off);
      inv[mi][r] = 1.f / vsum;
      #pragma unroll
      for (int ni = 0; ni < 4; ni++) {
        int col = ni * 16 + c;
        *(__hip_bfloat16*)(lds + ((row * 128 + col * 2) ^ ((row & 7) << 4))) =
            __float2bfloat16(p[ni]);
      }
    }
  }
  __syncthreads();

  // ---- O = P*V ----
  f32x4 oacc[4][2];
  #pragma unroll
  for (int mt = 0; mt < 4; mt++)
    #pragma unroll
    for (int nt = 0; nt < 2; nt++)
      oacc[mt][nt] = (f32x4){0.f, 0.f, 0.f, 0.f};
  #pragma unroll
  for (int ks = 0; ks < 2; ks++) {
    short8 vb[2];
    #pragma unroll
    for (int nt = 0; nt < 2; nt++) {
      int d = c + 16 * nt;
      vb[nt] = *(const short8*)(lds + 8192 +
                ((d * 128 + h * 16 + ks * 64) ^ ((d & 7) << 4)));
    }
    #pragma unroll
    for (int mt = 0; mt < 4; mt++) {
      int qr = c + 16 * mt;
      short8 pa = *(const short8*)(lds +
                   ((qr * 128 + h * 16 + ks * 64) ^ ((qr & 7) << 4)));
      #pragma unroll
      for (int nt = 0; nt < 2; nt++)
        oacc[mt][nt] = __builtin_amdgcn_mfma_f32_16x16x32_bf16(
            pa, vb[nt], oacc[mt][nt], 0, 0, 0);
    }
  }

  // ---- store (q < 49 only), normalize by 1/rowsum ----
  #pragma unroll
  for (int mt = 0; mt < 4; mt++) {
    #pragma unroll
    for (int r = 0; r < 4; r++) {
      int q = mt * 16 + h * 4 + r;
      if (q < 49) {
        __hip_bfloat16* orow = o + ((size_t)b_ * 49 + q) * 192 + headoff;
        #pragma unroll
        for (int nt = 0; nt < 2; nt++)
          orow[nt * 16 + c] = __float2bfloat16(oacc[mt][nt][r] * inv[mt][r]);
      }
    }
  }
}

// ---------------------------------------------------------------------------
extern "C" void kernel_launch(void* const* d_in, const int* in_sizes, int n_in,
                              void* d_out, int out_size, void* d_ws, size_t ws_size,
                              hipStream_t stream)
{
  const float* x      = (const float*)d_in[0];
  const float* mask   = (const float*)d_in[1];
  const float* n1g    = (const float*)d_in[2];
  const float* n1b    = (const float*)d_in[3];
  const float* qkv_w  = (const float*)d_in[4];
  const float* qkv_b  = (const float*)d_in[5];
  const float* proj_w = (const float*)d_in[6];
  const float* proj_b = (const float*)d_in[7];
  const float* rpb    = (const float*)d_in[8];
  const float* n2g    = (const float*)d_in[9];
  const float* n2b    = (const float*)d_in[10];
  const float* fc1_w  = (const float*)d_in[11];
  const float* fc1_b  = (const float*)d_in[12];
  const float* fc2_w  = (const float*)d_in[13];
  const float* fc2_b  = (const float*)d_in[14];
  float* out = (float*)d_out;

  // Workspace layout:
  //   A: 154.1 MB (qkv out bf16; later h fp8 [MTOT][768] = 77 MB)
  //   B:  38.5 MB (xw, attn-out, LN2 out)
  //   W:  0.7 MB bf16 weights (qkv|proj|fc1)   T: 3.1 MB softmax table
  //   X:  38.5 MB bf16 x2 residual   W8: 0.15 MB fp8 W2
  const size_t offA = 0;
  const size_t offB = offA + (size_t)100352 * 768 * 2;
  const size_t offW = offB + (size_t)100352 * 192 * 2;
  const size_t offT = offW + (size_t)(576*192 + 192*192 + 768*192) * 2;
  const size_t offX = offT + (size_t)384 * 4096 * 2;
  const size_t offW8 = offX + (size_t)100352 * 192 * 2;
  const size_t need = offW8 + (size_t)192 * 768;
  if (ws_size < need) return;  // avoid OOB writes

  char* ws = (char*)d_ws;
  __hip_bfloat16* bufA = (__hip_bfloat16*)(ws + offA);
  unsigned char*  h8   = (unsigned char*)(ws + offA);   // fc1 out (reuses A)
  __hip_bfloat16* bufB = (__hip_bfloat16*)(ws + offB);
  __hip_bfloat16* wq   = (__hip_bfloat16*)(ws + offW);
  __hip_bfloat16* wp   = wq + 576 * 192;
  __hip_bfloat16* w1   = wp + 192 * 192;
  __hip_bfloat16* tab  = (__hip_bfloat16*)(ws + offT);
  __hip_bfloat16* x2b  = (__hip_bfloat16*)(ws + offX);
  unsigned char*  w28  = (unsigned char*)(ws + offW8);

  // 1. weights -> bf16 (qkv|proj|fc1) and fc2 -> fp8 (x16)
  cvt4_kernel<<<1152, 256, 0, stream>>>(qkv_w, 576 * 192, proj_w, 192 * 192,
                                        fc1_w, 768 * 192, wq);
  cvtw2_kernel<<<576, 256, 0, stream>>>(fc2_w, w28);
  // 1b. softmax bias table
  smtab_kernel<<<384, 256, 0, stream>>>(mask, rpb, tab);
  // 2. LN1 + shift + window partition -> bf16 [MTOT][192]
  ln_kernel<true, false><<<MTOT / 4, 256, 0, stream>>>(x, n1g, n1b, bufB);
  // 3. qkv GEMM (XCD-coherent, 9 N-tiles) -> bf16 [MTOT][576]
  gemm_kernel<0, 192, 9><<<MP * 9, 256, 0, stream>>>(
      bufB, wq, qkv_b, 576, bufA, nullptr);
  // 4. windowed attention (MFMA) -> bf16 [MTOT][192]
  attn_kernel<<<dim3(2048, 6), 64, 0, stream>>>(bufA, tab, bufB);
  // 5. proj + window-reverse + unshift + residual -> bf16 x2 (3 N-tiles)
  gemm_kernel<4, 192, 3><<<MP * 3, 256, 0, stream>>>(
      bufB, wp, proj_b, 192, x2b, x);
  // 6. LN2 (bf16 input) -> bf16
  ln_kernel<false, true><<<MTOT / 4, 256, 0, stream>>>(x2b, n2g, n2b, bufB);
  // 7. fc1 + sigmoid GELU -> FP8 h [MTOT][768] (12 N-tiles)
  gemm_kernel<1, 192, 12><<<MP * 12, 256, 0, stream>>>(
      bufB, w1, fc1_b, 768, h8, nullptr);
  // 8. fc2 (fp8 MFMA) + residual(bf16 x2) -> fp32 out (3 N-tiles)
  gemm8_kernel<<<MP * 3, 256, 0, stream>>>(
      h8, w28, fc2_b, (const unsigned short*)x2b, out);
}